// Round 1
// baseline (306.972 us; speedup 1.0000x reference)
//
#include <hip/hip_runtime.h>
#include <math.h>

#define BN 32
#define NPTS 2048
#define MPTS 2048
#define ITERS 5
#define LOG2E 1.44269504088896340736f

// ws layout (in floats):
//  [0,192)    T      : per-batch affine 2x3 (r00,r01,tx,r10,r11,ty)
//  [192,448)  acc    : per-batch 8 reduction slots
//  [448,480)  maxt2  : per-batch max ||target||^2
//  [512, 512+BN*MPTS*4)  tp : per-target float4 (kx, ky, bm, 0)
#define T_OFF   0
#define ACC_OFF 192
#define MT2_OFF 448
#define TP_OFF  512

// ---------------------------------------------------------------------------
// Heavy kernel: one block = 64 rows of one batch; 4 waves each take a 512-wide
// M-chunk. Exponent = qpx*kx + qpy*ky + bm  (all log2-domain constants folded).
// ---------------------------------------------------------------------------
__global__ __launch_bounds__(256) void icp_rows(const float* __restrict__ source,
                                                float* __restrict__ ws) {
    __shared__ float4 tp_s[MPTS];  // 32 KB
    const int tid  = threadIdx.x;
    const int wave = tid >> 6;
    const int lane = tid & 63;
    const int b    = blockIdx.x >> 5;   // 32 blocks per batch
    const int blk  = blockIdx.x & 31;
    const int row  = (blk << 6) | lane; // row within batch [0,2048)

    const float* T = ws + T_OFF + b * 6;
    const float r00 = T[0], r01 = T[1], tx = T[2];
    const float r10 = T[3], r11 = T[4], ty = T[5];

    const float2 sp = ((const float2*)source)[b * NPTS + row];
    const float stx = fmaf(r00, sp.x, fmaf(r01, sp.y, tx));
    const float sty = fmaf(r10, sp.x, fmaf(r11, sp.y, ty));
    const float qpx = 2.0f * LOG2E * stx;
    const float qpy = 2.0f * LOG2E * sty;

    // stage this wave's 512-target chunk (wave-local: no barrier needed)
    const float4* tp = (const float4*)(ws + TP_OFF) + b * MPTS;
    const int m0 = wave << 9;
#pragma unroll
    for (int i = 0; i < 8; ++i) {
        const int m = m0 + (i << 6) + lane;
        tp_s[m] = tp[m];
    }

    float den0 = 0.f, ax0 = 0.f, ay0 = 0.f;
    float den1 = 0.f, ax1 = 0.f, ay1 = 0.f;
    const float4* cp = tp_s + m0;
#pragma unroll 4
    for (int i = 0; i < 512; i += 2) {
        const float4 t0 = cp[i];
        const float4 t1 = cp[i + 1];
        const float s0 = fmaf(qpx, t0.x, fmaf(qpy, t0.y, t0.z));
        const float s1 = fmaf(qpx, t1.x, fmaf(qpy, t1.y, t1.z));
        const float e0 = __builtin_amdgcn_exp2f(s0);
        const float e1 = __builtin_amdgcn_exp2f(s1);
        den0 += e0; ax0 = fmaf(e0, t0.x, ax0); ay0 = fmaf(e0, t0.y, ay0);
        den1 += e1; ax1 = fmaf(e1, t1.x, ax1); ay1 = fmaf(e1, t1.y, ay1);
    }
    float den = den0 + den1, ax = ax0 + ax1, ay = ay0 + ay1;

    // combine the 4 M-chunks across waves
    __syncthreads();
    tp_s[(wave << 6) | lane] = make_float4(den, ax, ay, 0.f);
    __syncthreads();
    if (wave == 0) {
        const float4 p0 = tp_s[lane];
        const float4 p1 = tp_s[64 + lane];
        const float4 p2 = tp_s[128 + lane];
        const float4 p3 = tp_s[192 + lane];
        den = p0.x + p1.x + p2.x + p3.x;
        ax  = p0.y + p1.y + p2.y + p3.y;
        ay  = p0.z + p1.z + p2.z + p3.z;
        const float tcx = ax / den;
        const float tcy = ay / den;
        float v[8] = {stx, sty, tcx, tcy,
                      stx * tcx, stx * tcy, sty * tcx, sty * tcy};
#pragma unroll
        for (int off = 32; off > 0; off >>= 1) {
#pragma unroll
            for (int j = 0; j < 8; ++j) v[j] += __shfl_xor(v[j], off, 64);
        }
        if (lane == 0) {
            float* acc = ws + ACC_OFF + b * 8;
#pragma unroll
            for (int j = 0; j < 8; ++j) atomicAdd(acc + j, v[j]);
        }
    }
}

// ---------------------------------------------------------------------------
// Per-batch transform update (closed-form 2x2 Kabsch via polar factor),
// then rewrite tp.z with the new per-batch softmax shift for the next pass.
// ---------------------------------------------------------------------------
__global__ __launch_bounds__(256) void icp_update(const float* __restrict__ source,
                                                  const float* __restrict__ target,
                                                  float* __restrict__ ws) {
    const int b = blockIdx.x;
    const int tid = threadIdx.x;
    __shared__ float shT[6];
    __shared__ float red[256];
    __shared__ float shC;

    if (tid == 0) {
        float* acc = ws + ACC_OFF + b * 8;
        const float Ssx = acc[0], Ssy = acc[1], Stcx = acc[2], Stcy = acc[3];
        const float Sxx = acc[4], Sxy = acc[5], Syx = acc[6], Syy = acc[7];
#pragma unroll
        for (int j = 0; j < 8; ++j) acc[j] = 0.f;  // re-zero for next pass

        const float invN = 1.0f / (float)NPTS;
        const float csx = Ssx * invN, csy = Ssy * invN;
        const float ctx = Stcx * invN, cty = Stcy * invN;
        const float Hxx = Sxx - Ssx * ctx;
        const float Hxy = Sxy - Ssx * cty;
        const float Hyx = Syx - Ssy * ctx;
        const float Hyy = Syy - Ssy * cty;
        // A = H^T ; R_delta = polar(A)
        const float a = Hxx, bb = Hyx, cc = Hxy, d = Hyy;
        const float det = a * d - bb * cc;
        float R00, R01, R10, R11;
        if (det >= 0.f) {
            const float x = a + d, y = cc - bb;
            const float r = fmaxf(sqrtf(x * x + y * y), 1e-30f);
            const float cth = x / r, sth = y / r;
            R00 = cth; R01 = -sth; R10 = sth; R11 = cth;
        } else {
            const float x = a - d, y = bb + cc;
            const float r = fmaxf(sqrtf(x * x + y * y), 1e-30f);
            const float p = x / r, q = y / r;
            R00 = p; R01 = q; R10 = q; R11 = -p;
        }
        const float tdx = ctx - (R00 * csx + R01 * csy);
        const float tdy = cty - (R10 * csx + R11 * csy);
        // vec2mat(delta) uses cos/sin of atan2(R10,R00): (R00,R10) is unit.
        const float cD = R00, sD = R10;
        float* Tw = ws + T_OFF + b * 6;
        const float o00 = Tw[0], o01 = Tw[1], otx = Tw[2];
        const float o10 = Tw[3], o11 = Tw[4], oty = Tw[5];
        const float n00 = cD * o00 - sD * o10;
        const float n01 = cD * o01 - sD * o11;
        const float ntx = cD * otx - sD * oty + tdx;
        const float n10 = sD * o00 + cD * o10;
        const float n11 = sD * o01 + cD * o11;
        const float nty = sD * otx + cD * oty + tdy;
        Tw[0] = n00; Tw[1] = n01; Tw[2] = ntx;
        Tw[3] = n10; Tw[4] = n11; Tw[5] = nty;
        shT[0] = n00; shT[1] = n01; shT[2] = ntx;
        shT[3] = n10; shT[4] = n11; shT[5] = nty;
    }
    __syncthreads();
    const float r00 = shT[0], r01 = shT[1], tx = shT[2];
    const float r10 = shT[3], r11 = shT[4], ty = shT[5];

    // max ||st||^2 under the NEW transform
    float mx = 0.f;
#pragma unroll
    for (int i = 0; i < 8; ++i) {
        const int n = tid + (i << 8);
        const float2 sp = ((const float2*)source)[b * NPTS + n];
        const float stx = fmaf(r00, sp.x, fmaf(r01, sp.y, tx));
        const float sty = fmaf(r10, sp.x, fmaf(r11, sp.y, ty));
        mx = fmaxf(mx, stx * stx + sty * sty);
    }
    red[tid] = mx; __syncthreads();
    for (int s = 128; s > 0; s >>= 1) {
        if (tid < s) red[tid] = fmaxf(red[tid], red[tid + s]);
        __syncthreads();
    }
    if (tid == 0) {
        const float maxt2 = ws[MT2_OFF + b];
        shC = 2.f * sqrtf(red[0] * maxt2) * LOG2E;  // >= max exponent (log2)
    }
    __syncthreads();
    const float Cp = shC;
    float4* tp = (float4*)(ws + TP_OFF) + b * MPTS;
#pragma unroll
    for (int i = 0; i < 8; ++i) {
        const int m = tid + (i << 8);
        const float2 kp = ((const float2*)target)[b * MPTS + m];
        const float tsq = kp.x * kp.x + kp.y * kp.y;
        tp[m] = make_float4(kp.x, kp.y, fmaf(-tsq, LOG2E, -Cp), 0.f);
    }
}

// ---------------------------------------------------------------------------
// Init: T from init_transformation, maxt2, acc=0, tp plane for iteration 1.
// ---------------------------------------------------------------------------
__global__ __launch_bounds__(256) void icp_init(const float* __restrict__ source,
                                                const float* __restrict__ target,
                                                const float* __restrict__ init_t,
                                                float* __restrict__ ws) {
    const int b = blockIdx.x;
    const int tid = threadIdx.x;
    __shared__ float shT[6];
    __shared__ float red[256];
    __shared__ float shC;
    __shared__ float shMT;

    if (tid == 0) {
        const float th = init_t[b * 3 + 0];
        const float txv = init_t[b * 3 + 1];
        const float tyv = init_t[b * 3 + 2];
        const float c = cosf(th), s = sinf(th);
        float* Tw = ws + T_OFF + b * 6;
        Tw[0] = c;  Tw[1] = -s; Tw[2] = txv;
        Tw[3] = s;  Tw[4] = c;  Tw[5] = tyv;
        shT[0] = c;  shT[1] = -s; shT[2] = txv;
        shT[3] = s;  shT[4] = c;  shT[5] = tyv;
        float* acc = ws + ACC_OFF + b * 8;
#pragma unroll
        for (int j = 0; j < 8; ++j) acc[j] = 0.f;
    }
    __syncthreads();

    float mt = 0.f;
#pragma unroll
    for (int i = 0; i < 8; ++i) {
        const int m = tid + (i << 8);
        const float2 kp = ((const float2*)target)[b * MPTS + m];
        mt = fmaxf(mt, kp.x * kp.x + kp.y * kp.y);
    }
    red[tid] = mt; __syncthreads();
    for (int s = 128; s > 0; s >>= 1) {
        if (tid < s) red[tid] = fmaxf(red[tid], red[tid + s]);
        __syncthreads();
    }
    if (tid == 0) { shMT = red[0]; ws[MT2_OFF + b] = red[0]; }
    __syncthreads();

    const float r00 = shT[0], r01 = shT[1], tx = shT[2];
    const float r10 = shT[3], r11 = shT[4], ty = shT[5];
    float mx = 0.f;
#pragma unroll
    for (int i = 0; i < 8; ++i) {
        const int n = tid + (i << 8);
        const float2 sp = ((const float2*)source)[b * NPTS + n];
        const float stx = fmaf(r00, sp.x, fmaf(r01, sp.y, tx));
        const float sty = fmaf(r10, sp.x, fmaf(r11, sp.y, ty));
        mx = fmaxf(mx, stx * stx + sty * sty);
    }
    red[tid] = mx; __syncthreads();
    for (int s = 128; s > 0; s >>= 1) {
        if (tid < s) red[tid] = fmaxf(red[tid], red[tid + s]);
        __syncthreads();
    }
    if (tid == 0) shC = 2.f * sqrtf(red[0] * shMT) * LOG2E;
    __syncthreads();

    const float Cp = shC;
    float4* tp = (float4*)(ws + TP_OFF) + b * MPTS;
#pragma unroll
    for (int i = 0; i < 8; ++i) {
        const int m = tid + (i << 8);
        const float2 kp = ((const float2*)target)[b * MPTS + m];
        const float tsq = kp.x * kp.x + kp.y * kp.y;
        tp[m] = make_float4(kp.x, kp.y, fmaf(-tsq, LOG2E, -Cp), 0.f);
    }
}

__global__ void icp_final(const float* __restrict__ ws, float* __restrict__ out) {
    const int b = threadIdx.x;
    if (b < BN) {
        const float* T = ws + T_OFF + b * 6;
        out[b * 3 + 0] = atan2f(T[3], T[0]);
        out[b * 3 + 1] = T[2];
        out[b * 3 + 2] = T[5];
    }
}

extern "C" void kernel_launch(void* const* d_in, const int* in_sizes, int n_in,
                              void* d_out, int out_size, void* d_ws, size_t ws_size,
                              hipStream_t stream) {
    const float* source = (const float*)d_in[0];
    const float* target = (const float*)d_in[1];
    const float* initt  = (const float*)d_in[2];
    float* out = (float*)d_out;
    float* ws  = (float*)d_ws;

    icp_init<<<BN, 256, 0, stream>>>(source, target, initt, ws);
    for (int it = 0; it < ITERS; ++it) {
        icp_rows<<<BN * 32, 256, 0, stream>>>(source, ws);
        icp_update<<<BN, 256, 0, stream>>>(source, target, ws);
    }
    icp_final<<<1, 64, 0, stream>>>(ws, out);
}